// Round 7
// baseline (214.086 us; speedup 1.0000x reference)
//
#include <hip/hip_runtime.h>
#include <hip/hip_bf16.h>
#include <math.h>

// TinyMoE: out = sum_e softmax(x@Wr)[e] * (gelu(x@w1[e]+b1[e]) @ w2[e] + b2[e])
// v8: fused kernel, 64-token tile, 4 waves, __launch_bounds__(256,3) -> 3 blocks/CU
//     (12 waves/CU, 1.5x the 51us config). LDS cut 67.6KB -> 54.3KB via K-chunked
//     double-buffered X staging ([64][64] bf16 chunks, XOR-swizzled) + swizzled
//     H[64][288]. GEMM2 runs two 64-col passes (acc[4][4]) to fit the 170-reg
//     budget. Per-wave ILP / weight traffic identical to the 51us kernel: this is
//     the clean occupancy experiment (v2/v3 spilled; v4 confounded weight traffic).

typedef short v8s __attribute__((ext_vector_type(8)));
typedef float v4f __attribute__((ext_vector_type(4)));

__device__ __forceinline__ unsigned short f2bf(float f) {
    unsigned int u = __builtin_bit_cast(unsigned int, f);
    u += 0x7fffu + ((u >> 16) & 1u);
    return (unsigned short)(u >> 16);
}
__device__ __forceinline__ unsigned int pk2(float lo, float hi) {
    return (unsigned int)f2bf(lo) | ((unsigned int)f2bf(hi) << 16);
}
// exact-gelu via A&S 7.1.26 erf (|err|<=1.5e-7; harness-verified in v7)
__device__ __forceinline__ float gelu_fast(float v) {
    float s  = v * 0.70710678118f;
    float xa = fabsf(s);
    float t  = 1.0f / (1.0f + 0.3275911f * xa);
    float poly = t * (0.254829592f + t * (-0.284496736f + t * (1.421413741f +
                 t * (-1.453152027f + t * 1.061405429f))));
    float er = copysignf(1.0f - poly * __expf(-xa * xa), s);
    return 0.5f * v * (1.0f + er);
}

// ---- prep: pack weights into bf16 MFMA B-fragment layout in workspace ----
__global__ void moe_prep(const float* __restrict__ w1,   // (4,512,64)
                         const float* __restrict__ w2,   // (4,64,512)
                         const float* __restrict__ b2,   // (4,512)
                         const float* __restrict__ rw,   // (512,4)
                         unsigned short* __restrict__ w1p,
                         unsigned short* __restrict__ w2p,
                         unsigned short* __restrict__ rp) {
    int idx = blockIdx.x * 256 + threadIdx.x;
    if (idx < 131072) {
        int block = idx >> 9, within = idx & 511;
        int kb = block >> 4, cb = block & 15;
        int n = within >> 5, kl = within & 31;
        int k = kb * 32 + kl;
        int col = cb * 16 + n;
        int e = col >> 6, h = col & 63;
        w1p[idx] = f2bf(w1[(e * 512 + k) * 64 + h]);
    } else if (idx < 131072 + 147456) {
        int op = idx - 131072;
        int block = op >> 9, within = op & 511;
        int kb = block >> 5, cb = block & 31;
        int n = within >> 5, kl = within & 31;
        int k = kb * 32 + kl;
        int d = cb * 16 + n;
        float v = 0.f;
        if (k < 256) {
            int e = k >> 6, h = k & 63;
            v = w2[(e * 64 + h) * 512 + d];
        } else if (k < 260) {
            v = b2[(k - 256) * 512 + d];
        }
        w2p[op] = f2bf(v);
    } else if (idx < 131072 + 147456 + 8192) {
        int op = idx - (131072 + 147456);
        int kb = op >> 9, within = op & 511;
        int n = within >> 5, kl = within & 31;
        int k = kb * 32 + kl;
        float v = (n < 4) ? rw[k * 4 + n] : 0.f;
        rp[op] = f2bf(v);
    }
}

// ---- main fused kernel ----
__global__ __launch_bounds__(256, 3)
void moe_main(const float* __restrict__ x,
              const float* __restrict__ rb,
              const float* __restrict__ b1,
              const unsigned short* __restrict__ w1p,
              const unsigned short* __restrict__ w2p,
              const unsigned short* __restrict__ rp,
              float* __restrict__ out) {
    // X K-chunk double buffer: [64 rows][64 bf16], row stride 128B, swizzled
    __shared__ __align__(16) unsigned short xc[2][64 * 64];   // 16384 B
    // H: [64 rows][288 bf16], row stride 576B, swizzled (bits 4..5)
    __shared__ __align__(16) unsigned short hl[64 * 288];     // 36864 B
    __shared__ float lw[64 * 4];                              // 1024 B  (total 54272 B)

    const int tid  = threadIdx.x;
    const int lane = tid & 63, wv = tid >> 6;
    const int lr = lane & 15, lq = lane >> 4;   // A: m=lr ; B: n=lr ; C: col=lr, row=lq*4+r
    const long t0 = (long)blockIdx.x * 64;

    const float4* xt = (const float4*)(x + t0 * 512);
    char* xcb0 = (char*)&xc[0][0];
    char* xcb1 = (char*)&xc[1][0];
    char* hlb  = (char*)&hl[0];

    // stage chunk kc (global cols kc*64..+64) into buffer b, swizzled 16B units
    #define STAGE(bptr, kc)                                                        \
        {                                                                          \
            _Pragma("unroll")                                                      \
            for (int s = 0; s < 2; ++s) {                                          \
                int F = s * 256 + tid;          /* 16B-unit index, 512 units */    \
                int row = F >> 3, u = F & 7;                                       \
                float4 v0 = xt[row * 128 + (kc) * 16 + u * 2];                     \
                float4 v1 = xt[row * 128 + (kc) * 16 + u * 2 + 1];                 \
                uint4 c = make_uint4(pk2(v0.x, v0.y), pk2(v0.z, v0.w),             \
                                     pk2(v1.x, v1.y), pk2(v1.z, v1.w));            \
                int bo = row * 128 + ((u * 16) ^ ((row & 7) << 4));                \
                *(uint4*)((bptr) + bo) = c;                                        \
            }                                                                      \
        }

    STAGE(xcb0, 0);
    __syncthreads();

    // ---- GEMM1  C1[64][256] = X @ W1'; wave w = expert w (cols 64w..64w+64).
    //      Router logits for rows 16w..16w+15 folded in (reuses a[wv]). ----
    v4f acc1[4][4];
    v4f accR;
    accR[0] = accR[1] = accR[2] = accR[3] = 0.f;
    #pragma unroll
    for (int mt = 0; mt < 4; ++mt)
        #pragma unroll
        for (int nt = 0; nt < 4; ++nt)
            acc1[mt][nt][0] = acc1[mt][nt][1] = acc1[mt][nt][2] = acc1[mt][nt][3] = 0.f;

    #pragma unroll 1
    for (int kc = 0; kc < 8; ++kc) {
        char* rdb = (kc & 1) ? xcb1 : xcb0;
        char* wrb = (kc & 1) ? xcb0 : xcb1;
        if (kc < 7) STAGE(wrb, kc + 1);
        #pragma unroll
        for (int k2 = 0; k2 < 2; ++k2) {
            int kb = kc * 2 + k2;
            v8s a[4], b[4];
            #pragma unroll
            for (int mt = 0; mt < 4; ++mt) {
                int row = 16 * mt + lr;
                int bo = row * 128 + ((k2 * 64 + lq * 16) ^ ((lr & 7) << 4));
                a[mt] = *(const v8s*)(rdb + bo);
            }
            #pragma unroll
            for (int nt = 0; nt < 4; ++nt)
                b[nt] = *(const v8s*)(const void*)&w1p[(size_t)(kb * 16 + wv * 4 + nt) * 512 + lr * 32 + lq * 8];
            v8s br = *(const v8s*)(const void*)&rp[kb * 512 + lr * 32 + lq * 8];
            accR = __builtin_amdgcn_mfma_f32_16x16x32_bf16(a[wv], br, accR, 0, 0, 0);
            #pragma unroll
            for (int mt = 0; mt < 4; ++mt)
                #pragma unroll
                for (int nt = 0; nt < 4; ++nt)
                    acc1[mt][nt] = __builtin_amdgcn_mfma_f32_16x16x32_bf16(a[mt], b[nt], acc1[mt][nt], 0, 0, 0);
        }
        if (kc < 7) __syncthreads();
    }

    // ---- in-register softmax: accR[r] = logit(row = 16wv + lq*4 + r, expert = lr) ----
    {
        float rbv = rb[lane & 3];
        #pragma unroll
        for (int r = 0; r < 4; ++r) {
            float v = accR[r] + rbv;
            float m = fmaxf(v, __shfl_xor(v, 1));
            m = fmaxf(m, __shfl_xor(m, 2));
            float e = __expf(v - m);
            float s = e + __shfl_xor(e, 1);
            s += __shfl_xor(s, 2);
            if (lr < 4)
                lw[(16 * wv + lq * 4 + r) * 4 + lr] = e / s;
        }
    }
    __syncthreads();   // lw visible

    // ---- epilogue: gelu(v+b1)*wt -> swizzled H[64][288]; cols 256..259 = wt, 260.. = 0 ----
    {
        float b1v[4];
        #pragma unroll
        for (int nt = 0; nt < 4; ++nt) b1v[nt] = b1[wv * 64 + nt * 16 + lr];
        #pragma unroll
        for (int mt = 0; mt < 4; ++mt) {
            #pragma unroll
            for (int r = 0; r < 4; ++r) {
                int row = 16 * mt + lq * 4 + r;
                float wt = lw[row * 4 + wv];
                #pragma unroll
                for (int nt = 0; nt < 4; ++nt) {
                    float v = acc1[mt][nt][r] + b1v[nt];
                    float g = gelu_fast(v) * wt;
                    int col = wv * 64 + nt * 16 + lr;
                    int bo = row * 576 + ((col * 2) ^ ((row & 3) << 4));
                    *(unsigned short*)(hlb + bo) = f2bf(g);
                }
            }
        }
        // wt cols 256..259 and zero cols 260..287
        int row = tid >> 2, j = tid & 3;
        {
            int bo = row * 576 + (((256 + j) * 2) ^ ((row & 3) << 4));
            *(unsigned short*)(hlb + bo) = f2bf(lw[tid]);
        }
        #pragma unroll
        for (int i = 0; i < 7; ++i) {
            int col = 260 + j * 7 + i;
            int bo = row * 576 + ((col * 2) ^ ((row & 3) << 4));
            *(unsigned short*)(hlb + bo) = 0;
        }
    }
    __syncthreads();

    // ---- GEMM2  OUT[64][512] = H @ W2'; wave w owns cols [128w,128w+128),
    //      executed as two 64-col passes to keep acc at 4x4 (reg budget 170). ----
    float* ot = out + t0 * 512;
    #pragma unroll 1
    for (int half = 0; half < 2; ++half) {
        v4f acc2[4][4];
        #pragma unroll
        for (int mt = 0; mt < 4; ++mt)
            #pragma unroll
            for (int nt = 0; nt < 4; ++nt)
                acc2[mt][nt][0] = acc2[mt][nt][1] = acc2[mt][nt][2] = acc2[mt][nt][3] = 0.f;

        for (int kb = 0; kb < 9; ++kb) {
            v8s a[4], b[4];
            #pragma unroll
            for (int mt = 0; mt < 4; ++mt) {
                int row = 16 * mt + lr;
                int bo = row * 576 + ((kb * 64 + lq * 16) ^ ((lr & 3) << 4));
                a[mt] = *(const v8s*)(hlb + bo);
            }
            #pragma unroll
            for (int nt = 0; nt < 4; ++nt)
                b[nt] = *(const v8s*)(const void*)&w2p[(size_t)(kb * 32 + wv * 8 + half * 4 + nt) * 512 + lr * 32 + lq * 8];
            #pragma unroll
            for (int mt = 0; mt < 4; ++mt)
                #pragma unroll
                for (int nt = 0; nt < 4; ++nt)
                    acc2[mt][nt] = __builtin_amdgcn_mfma_f32_16x16x32_bf16(a[mt], b[nt], acc2[mt][nt], 0, 0, 0);
        }

        #pragma unroll
        for (int mt = 0; mt < 4; ++mt)
            #pragma unroll
            for (int nt = 0; nt < 4; ++nt)
                #pragma unroll
                for (int r = 0; r < 4; ++r) {
                    int row = 16 * mt + lq * 4 + r;
                    int col = 128 * wv + 64 * half + 16 * nt + lr;
                    ot[row * 512 + col] = acc2[mt][nt][r];
                }
    }
    #undef STAGE
}

extern "C" void kernel_launch(void* const* d_in, const int* in_sizes, int n_in,
                              void* d_out, int out_size, void* d_ws, size_t ws_size,
                              hipStream_t stream) {
    const float* x  = (const float*)d_in[0];
    const float* rw = (const float*)d_in[1];
    const float* rb = (const float*)d_in[2];
    const float* w1 = (const float*)d_in[3];
    const float* b1 = (const float*)d_in[4];
    const float* w2 = (const float*)d_in[5];
    const float* b2 = (const float*)d_in[6];

    unsigned short* w1p = (unsigned short*)d_ws;      // 131072 elems
    unsigned short* w2p = w1p + 131072;               // 147456 elems
    unsigned short* rp  = w2p + 147456;               // 8192 elems  (total ~573 KB)

    moe_prep<<<1120, 256, 0, stream>>>(w1, w2, b2, rw, w1p, w2p, rp);
    moe_main<<<512, 256, 0, stream>>>(x, rb, b1, w1p, w2p, rp, (float*)d_out);
}

// Round 8
// 150.092 us; speedup vs baseline: 1.4264x; 1.4264x over previous
//
#include <hip/hip_runtime.h>
#include <hip/hip_bf16.h>
#include <math.h>

// TinyMoE: out = sum_e softmax(x@Wr)[e] * (gelu(x@w1[e]+b1[e]) @ w2[e] + b2[e])
// v9: v1/v5 geometry (64 tok/WG, 4 waves, (256,2), 2 blocks/CU, no spill) +
//     HAND-PIPELINED weight prefetch: named double-buffered b-fragment registers,
//     kb+1's global loads issued before kb's LDS reads + MFMAs (load-to-use
//     distance ~250-300cy covers L2 latency; compiler provably doesn't do this:
//     v6 unroll-2 neutral). GEMM2 runs as two 64-col halves (acc 64 each) so
//     prefetch regs fit; half-0 stores overlap half-1 compute (spreads write burst).
//     Router fold + in-reg softmax (v5), gelu_fast (v7-verified).

typedef short v8s __attribute__((ext_vector_type(8)));
typedef float v4f __attribute__((ext_vector_type(4)));

#define XS 520   // X LDS row stride (bf16): 512 + 8 pad
#define HS 296   // H LDS row stride: 288 (256 + 4 b2 rows + 28 zero) + 8 pad

__device__ __forceinline__ unsigned short f2bf(float f) {
    unsigned int u = __builtin_bit_cast(unsigned int, f);
    u += 0x7fffu + ((u >> 16) & 1u);
    return (unsigned short)(u >> 16);
}
// exact-gelu via A&S 7.1.26 erf (|err|<=1.5e-7; harness-verified v7/v8)
__device__ __forceinline__ float gelu_fast(float v) {
    float s  = v * 0.70710678118f;
    float xa = fabsf(s);
    float t  = 1.0f / (1.0f + 0.3275911f * xa);
    float poly = t * (0.254829592f + t * (-0.284496736f + t * (1.421413741f +
                 t * (-1.453152027f + t * 1.061405429f))));
    float er = copysignf(1.0f - poly * __expf(-xa * xa), s);
    return 0.5f * v * (1.0f + er);
}

// ---- prep: pack weights into bf16 MFMA B-fragment layout (unchanged, verified) ----
__global__ void moe_prep(const float* __restrict__ w1,   // (4,512,64)
                         const float* __restrict__ w2,   // (4,64,512)
                         const float* __restrict__ b2,   // (4,512)
                         const float* __restrict__ rw,   // (512,4)
                         unsigned short* __restrict__ w1p,
                         unsigned short* __restrict__ w2p,
                         unsigned short* __restrict__ rp) {
    int idx = blockIdx.x * 256 + threadIdx.x;
    if (idx < 131072) {
        int block = idx >> 9, within = idx & 511;
        int kb = block >> 4, cb = block & 15;
        int n = within >> 5, kl = within & 31;
        int k = kb * 32 + kl;
        int col = cb * 16 + n;
        int e = col >> 6, h = col & 63;
        w1p[idx] = f2bf(w1[(e * 512 + k) * 64 + h]);
    } else if (idx < 131072 + 147456) {
        int op = idx - 131072;
        int block = op >> 9, within = op & 511;
        int kb = block >> 5, cb = block & 31;
        int n = within >> 5, kl = within & 31;
        int k = kb * 32 + kl;
        int d = cb * 16 + n;
        float v = 0.f;
        if (k < 256) {
            int e = k >> 6, h = k & 63;
            v = w2[(e * 64 + h) * 512 + d];
        } else if (k < 260) {
            v = b2[(k - 256) * 512 + d];
        }
        w2p[op] = f2bf(v);
    } else if (idx < 131072 + 147456 + 8192) {
        int op = idx - (131072 + 147456);
        int kb = op >> 9, within = op & 511;
        int n = within >> 5, kl = within & 31;
        int k = kb * 32 + kl;
        float v = (n < 4) ? rw[k * 4 + n] : 0.f;
        rp[op] = f2bf(v);
    }
}

// ---- main fused kernel ----
__global__ __launch_bounds__(256, 2)
void moe_main(const float* __restrict__ x,
              const float* __restrict__ rb,
              const float* __restrict__ b1,
              const unsigned short* __restrict__ w1p,
              const unsigned short* __restrict__ w2p,
              const unsigned short* __restrict__ rp,
              float* __restrict__ out) {
    __shared__ __align__(16) unsigned short lx[64 * XS];   // X tile; H aliases after GEMM1
    __shared__ float lw[64 * 4];

    const int tid  = threadIdx.x;
    const int lane = tid & 63, wv = tid >> 6;
    const int lr = lane & 15, lq = lane >> 4;   // A: m=lr ; B: n=lr ; C: col=lr, row=lq*4+r
    const long t0 = (long)blockIdx.x * 64;

    // ---- phase 0: stage X tile (fp32 global -> bf16 LDS) ----
    const float4* xt = (const float4*)(x + t0 * 512);
    #pragma unroll
    for (int it = 0; it < 32; ++it) {
        int F = it * 256 + tid;
        int row = F >> 7, c4 = F & 127;
        float4 v = xt[F];
        unsigned int p0 = (unsigned int)f2bf(v.x) | ((unsigned int)f2bf(v.y) << 16);
        unsigned int p1 = (unsigned int)f2bf(v.z) | ((unsigned int)f2bf(v.w) << 16);
        *(uint2*)&lx[row * XS + c4 * 4] = make_uint2(p0, p1);
    }
    __syncthreads();

    // ---- GEMM1 with hand prefetch: wave w = expert w (cols 64w..64w+64) + router rows 16w.. ----
    v4f acc1[4][4];
    v4f accR;
    accR[0] = accR[1] = accR[2] = accR[3] = 0.f;
    #pragma unroll
    for (int mt = 0; mt < 4; ++mt)
        #pragma unroll
        for (int nt = 0; nt < 4; ++nt)
            acc1[mt][nt][0] = acc1[mt][nt][1] = acc1[mt][nt][2] = acc1[mt][nt][3] = 0.f;

    const unsigned short* w1base = w1p + (size_t)(wv * 4) * 512 + lr * 32 + lq * 8;
    const unsigned short* rpbase = rp + lr * 32 + lq * 8;

    #define LDW1(B, BR, kb) do {                                                   \
        _Pragma("unroll")                                                          \
        for (int nt_ = 0; nt_ < 4; ++nt_)                                          \
            B[nt_] = *(const v8s*)(const void*)&w1base[(size_t)((kb) * 16 + nt_) * 512]; \
        BR = *(const v8s*)(const void*)&rpbase[(kb) * 512];                        \
    } while (0)

    #define MM1(B, BR, kb) do {                                                    \
        v8s a_[4];                                                                 \
        _Pragma("unroll")                                                          \
        for (int mt_ = 0; mt_ < 4; ++mt_)                                          \
            a_[mt_] = *(const v8s*)(const void*)&lx[(16 * mt_ + lr) * XS + (kb) * 32 + lq * 8]; \
        v8s ar_ = *(const v8s*)(const void*)&lx[(16 * wv + lr) * XS + (kb) * 32 + lq * 8];      \
        accR = __builtin_amdgcn_mfma_f32_16x16x32_bf16(ar_, BR, accR, 0, 0, 0);    \
        _Pragma("unroll")                                                          \
        for (int mt_ = 0; mt_ < 4; ++mt_)                                          \
            _Pragma("unroll")                                                      \
            for (int nt_ = 0; nt_ < 4; ++nt_)                                      \
                acc1[mt_][nt_] = __builtin_amdgcn_mfma_f32_16x16x32_bf16(a_[mt_], B[nt_], acc1[mt_][nt_], 0, 0, 0); \
    } while (0)

    {
        v8s b0[4], b1[4], br0, br1;
        LDW1(b0, br0, 0);
        #pragma unroll
        for (int kp = 0; kp < 8; ++kp) {
            LDW1(b1, br1, 2 * kp + 1);          // prefetch odd kb
            MM1(b0, br0, 2 * kp);               // compute even kb
            if (kp < 7) LDW1(b0, br0, 2 * kp + 2);  // prefetch next even kb
            MM1(b1, br1, 2 * kp + 1);           // compute odd kb
        }
    }

    // ---- in-register softmax: accR[r] = logit(row = 16wv + lq*4 + r, expert = lr) ----
    {
        float rbv = rb[lane & 3];
        #pragma unroll
        for (int r = 0; r < 4; ++r) {
            float v = accR[r] + rbv;
            float m = fmaxf(v, __shfl_xor(v, 1));
            m = fmaxf(m, __shfl_xor(m, 2));
            float e = __expf(v - m);
            float s = e + __shfl_xor(e, 1);
            s += __shfl_xor(s, 2);
            if (lr < 4)
                lw[(16 * wv + lq * 4 + r) * 4 + lr] = e / s;
        }
    }
    __syncthreads();   // lw visible; all waves done reading X; lx may now hold H

    const unsigned short* w2base = w2p + (size_t)(wv * 8) * 512 + lr * 32 + lq * 8;

    // prefetch GEMM2 half-0 kb-0 weights during the epilogue
    v8s c0[4], c1[4];
    #pragma unroll
    for (int nt_ = 0; nt_ < 4; ++nt_)
        c0[nt_] = *(const v8s*)(const void*)&w2base[(size_t)nt_ * 512];

    // ---- epilogue: gelu(v+b1)*wt -> bf16 H[64][288] (aliasing lx) ----
    {
        float b1v[4];
        #pragma unroll
        for (int nt = 0; nt < 4; ++nt) b1v[nt] = b1[wv * 64 + nt * 16 + lr];
        #pragma unroll
        for (int mt = 0; mt < 4; ++mt) {
            #pragma unroll
            for (int r = 0; r < 4; ++r) {
                int row = 16 * mt + lq * 4 + r;
                float wt = lw[row * 4 + wv];
                #pragma unroll
                for (int nt = 0; nt < 4; ++nt) {
                    float v = acc1[mt][nt][r] + b1v[nt];
                    float g = gelu_fast(v) * wt;
                    lx[row * HS + wv * 64 + nt * 16 + lr] = f2bf(g);
                }
            }
        }
        // router-weight cols (256..259) and zero pad (260..287)
        int r = tid >> 2, e = tid & 3;
        lx[r * HS + 256 + e] = f2bf(lw[tid]);
        #pragma unroll
        for (int i = 0; i < 7; ++i)
            lx[r * HS + 260 + e + 4 * i] = 0;
    }
    __syncthreads();

    // ---- GEMM2: OUT[64][512] = H[64][288] @ W2'; wave w cols [128w,128w+128),
    //      two 64-col halves, hand-prefetched; half-0 stores overlap half-1 compute ----
    float* ot = out + t0 * 512;

    #define LDW2(C, kb, h) do {                                                    \
        _Pragma("unroll")                                                          \
        for (int nt_ = 0; nt_ < 4; ++nt_)                                          \
            C[nt_] = *(const v8s*)(const void*)&w2base[(size_t)((kb) * 32 + (h) * 4 + nt_) * 512]; \
    } while (0)

    #define MM2(C, kb) do {                                                        \
        v8s a_[4];                                                                 \
        _Pragma("unroll")                                                          \
        for (int mt_ = 0; mt_ < 4; ++mt_)                                          \
            a_[mt_] = *(const v8s*)(const void*)&lx[(16 * mt_ + lr) * HS + (kb) * 32 + lq * 8]; \
        _Pragma("unroll")                                                          \
        for (int mt_ = 0; mt_ < 4; ++mt_)                                          \
            _Pragma("unroll")                                                      \
            for (int nt_ = 0; nt_ < 4; ++nt_)                                      \
                acc2[mt_][nt_] = __builtin_amdgcn_mfma_f32_16x16x32_bf16(a_[mt_], C[nt_], acc2[mt_][nt_], 0, 0, 0); \
    } while (0)

    #pragma unroll 1
    for (int half = 0; half < 2; ++half) {
        v4f acc2[4][4];
        #pragma unroll
        for (int mt = 0; mt < 4; ++mt)
            #pragma unroll
            for (int nt = 0; nt < 4; ++nt)
                acc2[mt][nt][0] = acc2[mt][nt][1] = acc2[mt][nt][2] = acc2[mt][nt][3] = 0.f;

        // c0 holds kb=0 for this half (prefetched during epilogue / previous half tail)
        #pragma unroll
        for (int kp = 0; kp < 4; ++kp) {
            LDW2(c1, 2 * kp + 1, half);
            MM2(c0, 2 * kp);
            LDW2(c0, 2 * kp + 2, half);
            MM2(c1, 2 * kp + 1);
        }
        if (half == 0) {
            // prefetch half-1 kb0 into c1 before the tail so it's in flight during stores
            LDW2(c1, 0, 1);
        }
        MM2(c0, 8);   // tail kb

        #pragma unroll
        for (int mt = 0; mt < 4; ++mt)
            #pragma unroll
            for (int nt = 0; nt < 4; ++nt)
                #pragma unroll
                for (int r = 0; r < 4; ++r) {
                    int row = 16 * mt + lq * 4 + r;
                    int col = 128 * wv + 64 * half + 16 * nt + lr;
                    ot[row * 512 + col] = acc2[mt][nt][r];
                }

        if (half == 0) {
            // rotate: c1 (half-1 kb0) becomes c0 for the next pass
            #pragma unroll
            for (int nt_ = 0; nt_ < 4; ++nt_) c0[nt_] = c1[nt_];
        }
    }
    #undef LDW1
    #undef MM1
    #undef LDW2
    #undef MM2
}

extern "C" void kernel_launch(void* const* d_in, const int* in_sizes, int n_in,
                              void* d_out, int out_size, void* d_ws, size_t ws_size,
                              hipStream_t stream) {
    const float* x  = (const float*)d_in[0];
    const float* rw = (const float*)d_in[1];
    const float* rb = (const float*)d_in[2];
    const float* w1 = (const float*)d_in[3];
    const float* b1 = (const float*)d_in[4];
    const float* w2 = (const float*)d_in[5];
    const float* b2 = (const float*)d_in[6];

    unsigned short* w1p = (unsigned short*)d_ws;      // 131072 elems
    unsigned short* w2p = w1p + 131072;               // 147456 elems
    unsigned short* rp  = w2p + 147456;               // 8192 elems

    moe_prep<<<1120, 256, 0, stream>>>(w1, w2, b2, rw, w1p, w2p, rp);
    moe_main<<<512, 256, 0, stream>>>(x, rb, b1, w1p, w2p, rp, (float*)d_out);
}

// Round 9
// 148.529 us; speedup vs baseline: 1.4414x; 1.0105x over previous
//
#include <hip/hip_runtime.h>
#include <hip/hip_bf16.h>
#include <math.h>

// TinyMoE: out = sum_e softmax(x@Wr)[e] * (gelu(x@w1[e]+b1[e]) @ w2[e] + b2[e])
// v10: v1 shell (64 tok/WG, 4 waves, (256,2), no spill) ported from 16x16x32 to
//      32x32x16 MFMA: half the MFMA instructions (560->280/wave), ~12% less pipe
//      time per FLOP (m119: 2495 vs 2176 TF), longer per-instr latency window for
//      the co-wave at 2 waves/SIMD. Fragment layouts: A row=lane&31,
//      k=(lane>>5)*8+j ; B col=lane&31, same k ; C/D col=lane&31,
//      row=(reg&3)+8*(reg>>2)+4*(lane>>5) (guide-verified). Router folded on
//      waves 0-1 (32-row tiles), in-reg softmax, H aliases X LDS.

typedef short v8s  __attribute__((ext_vector_type(8)));
typedef float v16f __attribute__((ext_vector_type(16)));

#define XS 520   // X LDS row stride (bf16): 512 + 8 pad
#define HS 296   // H LDS row stride: 288 (256 + 4 b2 rows + 28 zero) + 8 pad

__device__ __forceinline__ unsigned short f2bf(float f) {
    unsigned int u = __builtin_bit_cast(unsigned int, f);
    u += 0x7fffu + ((u >> 16) & 1u);
    return (unsigned short)(u >> 16);
}
// exact-gelu via A&S 7.1.26 erf (|err|<=1.5e-7; harness-verified v7/v8)
__device__ __forceinline__ float gelu_fast(float v) {
    float s  = v * 0.70710678118f;
    float xa = fabsf(s);
    float t  = 1.0f / (1.0f + 0.3275911f * xa);
    float poly = t * (0.254829592f + t * (-0.284496736f + t * (1.421413741f +
                 t * (-1.453152027f + t * 1.061405429f))));
    float er = copysignf(1.0f - poly * __expf(-xa * xa), s);
    return 0.5f * v * (1.0f + er);
}

// ---- prep: pack weights into 32x32x16 B-fragment layout ----
// Block = 32(N) x 16(K) bf16, [n_local*16 + k_local], 512 elems = 1KB.
// Lane l reads 16B at ((l&31)*16 + (l>>5)*8)*2 -> B[k][n], n=l&31, k=(l>>5)*8+j.
__global__ void moe_prep(const float* __restrict__ w1,   // (4,512,64)
                         const float* __restrict__ w2,   // (4,64,512)
                         const float* __restrict__ b2,   // (4,512)
                         const float* __restrict__ rw,   // (512,4)
                         unsigned short* __restrict__ w1p,
                         unsigned short* __restrict__ w2p,
                         unsigned short* __restrict__ rp) {
    int idx = blockIdx.x * 256 + threadIdx.x;
    if (idx < 131072) {
        // W1' [K=512 -> 32 ksteps][8 col-blocks of 32]; col in [0,256)
        int block = idx >> 9, within = idx & 511;
        int kstep = block >> 3, cb = block & 7;
        int n = within >> 4, kl = within & 15;
        int k = kstep * 16 + kl;
        int col = cb * 32 + n;          // e = col>>6, h = col&63
        int e = col >> 6, h = col & 63;
        w1p[idx] = f2bf(w1[(e * 512 + k) * 64 + h]);
    } else if (idx < 131072 + 147456) {
        // W2' [Kpad=288 -> 18 ksteps][16 col-blocks of 32]; k 256..259 = b2, >=260 zero
        int op = idx - 131072;
        int block = op >> 9, within = op & 511;
        int kstep = block >> 4, cb = block & 15;
        int n = within >> 4, kl = within & 15;
        int k = kstep * 16 + kl;
        int d = cb * 32 + n;
        float v = 0.f;
        if (k < 256) {
            int e = k >> 6, h = k & 63;
            v = w2[(e * 64 + h) * 512 + d];
        } else if (k < 260) {
            v = b2[(k - 256) * 512 + d];
        }
        w2p[op] = f2bf(v);
    } else if (idx < 131072 + 147456 + 16384) {
        // router W [K=512 -> 32 ksteps][N=32, cols >=4 zero]
        int op = idx - (131072 + 147456);
        int kstep = op >> 9, within = op & 511;
        int n = within >> 4, kl = within & 15;
        int k = kstep * 16 + kl;
        float v = (n < 4) ? rw[k * 4 + n] : 0.f;
        rp[op] = f2bf(v);
    }
}

// ---- main fused kernel ----
__global__ __launch_bounds__(256, 2)
void moe_main(const float* __restrict__ x,
              const float* __restrict__ rb,
              const float* __restrict__ b1,
              const unsigned short* __restrict__ w1p,
              const unsigned short* __restrict__ w2p,
              const unsigned short* __restrict__ rp,
              float* __restrict__ out) {
    __shared__ __align__(16) unsigned short lx[64 * XS];   // X tile; H aliases after GEMM1
    __shared__ float lw[64 * 4];

    const int tid  = threadIdx.x;
    const int lane = tid & 63, wv = tid >> 6;
    const int ln = lane & 31, hi = lane >> 5;   // 32x32 frags: row/col=ln, k=hi*8+j
    const long t0 = (long)blockIdx.x * 64;

    // ---- phase 0: stage X tile (fp32 global -> bf16 LDS), unchanged from v1 ----
    const float4* xt = (const float4*)(x + t0 * 512);
    #pragma unroll
    for (int it = 0; it < 32; ++it) {
        int F = it * 256 + tid;
        int row = F >> 7, c4 = F & 127;
        float4 v = xt[F];
        unsigned int p0 = (unsigned int)f2bf(v.x) | ((unsigned int)f2bf(v.y) << 16);
        unsigned int p1 = (unsigned int)f2bf(v.z) | ((unsigned int)f2bf(v.w) << 16);
        *(uint2*)&lx[row * XS + c4 * 4] = make_uint2(p0, p1);
    }
    __syncthreads();

    // ---- GEMM1: C1[64][256] = X @ W1'. Wave w = expert w (cols 64w..64w+64, 2 ntiles).
    //      Waves 0-1 also accumulate router logits (rows 32wv..32wv+31). ----
    v16f acc1[2][2];
    v16f accR;
    #pragma unroll
    for (int j = 0; j < 16; ++j) accR[j] = 0.f;
    #pragma unroll
    for (int mt = 0; mt < 2; ++mt)
        #pragma unroll
        for (int nt = 0; nt < 2; ++nt)
            #pragma unroll
            for (int j = 0; j < 16; ++j) acc1[mt][nt][j] = 0.f;

    const unsigned short* w1b = w1p + (size_t)(wv * 2) * 512 + ln * 16 + hi * 8;
    const unsigned short* rpb = rp + ln * 16 + hi * 8;

    for (int ks = 0; ks < 32; ++ks) {
        v8s a0 = *(const v8s*)(const void*)&lx[ln * XS + ks * 16 + hi * 8];
        v8s a1 = *(const v8s*)(const void*)&lx[(32 + ln) * XS + ks * 16 + hi * 8];
        v8s b0 = *(const v8s*)(const void*)&w1b[(size_t)ks * 4096];
        v8s b1f = *(const v8s*)(const void*)&w1b[(size_t)ks * 4096 + 512];
        if (wv < 2) {
            v8s br = *(const v8s*)(const void*)&rpb[ks * 512];
            v8s ar = (wv == 0) ? a0 : a1;
            accR = __builtin_amdgcn_mfma_f32_32x32x16_bf16(ar, br, accR, 0, 0, 0);
        }
        acc1[0][0] = __builtin_amdgcn_mfma_f32_32x32x16_bf16(a0, b0, acc1[0][0], 0, 0, 0);
        acc1[0][1] = __builtin_amdgcn_mfma_f32_32x32x16_bf16(a0, b1f, acc1[0][1], 0, 0, 0);
        acc1[1][0] = __builtin_amdgcn_mfma_f32_32x32x16_bf16(a1, b0, acc1[1][0], 0, 0, 0);
        acc1[1][1] = __builtin_amdgcn_mfma_f32_32x32x16_bf16(a1, b1f, acc1[1][1], 0, 0, 0);
    }

    // ---- in-reg softmax (waves 0-1): accR[j] = logit(row = 32wv + (j&3)+8*(j>>2)+4*hi,
    //      expert = ln) valid for ln<4; 4-lane shfl_xor groups {0..3},{32..35} ----
    if (wv < 2) {
        float rbv = rb[ln & 3];
        #pragma unroll
        for (int j = 0; j < 16; ++j) {
            float v = accR[j] + rbv;
            float m = fmaxf(v, __shfl_xor(v, 1));
            m = fmaxf(m, __shfl_xor(m, 2));
            float e = __expf(v - m);
            float s = e + __shfl_xor(e, 1);
            s += __shfl_xor(s, 2);
            if (ln < 4) {
                int row = 32 * wv + (j & 3) + 8 * (j >> 2) + 4 * hi;
                lw[row * 4 + ln] = e / s;
            }
        }
    }
    __syncthreads();   // lw visible; all waves done reading X; lx may now hold H

    // ---- epilogue: gelu(v+b1)*wt -> bf16 H[64][288] (aliasing lx) ----
    {
        float b1v[2];
        #pragma unroll
        for (int nt = 0; nt < 2; ++nt) b1v[nt] = b1[wv * 64 + 32 * nt + ln];
        #pragma unroll
        for (int mt = 0; mt < 2; ++mt) {
            #pragma unroll
            for (int j = 0; j < 16; ++j) {
                int row = 32 * mt + (j & 3) + 8 * (j >> 2) + 4 * hi;
                float wt = lw[row * 4 + wv];
                #pragma unroll
                for (int nt = 0; nt < 2; ++nt) {
                    float v = acc1[mt][nt][j] + b1v[nt];
                    float g = gelu_fast(v) * wt;
                    lx[row * HS + wv * 64 + 32 * nt + ln] = f2bf(g);
                }
            }
        }
        // router-weight cols (256..259) and zero pad (260..287)
        int r = tid >> 2, e = tid & 3;
        lx[r * HS + 256 + e] = f2bf(lw[tid]);
        #pragma unroll
        for (int i = 0; i < 7; ++i)
            lx[r * HS + 260 + e + 4 * i] = 0;
    }
    __syncthreads();

    // ---- GEMM2: OUT[64][512] = H[64][288] @ W2'. Wave w cols [128w,128w+128) = 4 ntiles. ----
    v16f acc2[2][4];
    #pragma unroll
    for (int mt = 0; mt < 2; ++mt)
        #pragma unroll
        for (int nt = 0; nt < 4; ++nt)
            #pragma unroll
            for (int j = 0; j < 16; ++j) acc2[mt][nt][j] = 0.f;

    const unsigned short* w2b = w2p + (size_t)(wv * 4) * 512 + ln * 16 + hi * 8;

    for (int ks = 0; ks < 18; ++ks) {
        v8s a0 = *(const v8s*)(const void*)&lx[ln * HS + ks * 16 + hi * 8];
        v8s a1 = *(const v8s*)(const void*)&lx[(32 + ln) * HS + ks * 16 + hi * 8];
        v8s b[4];
        #pragma unroll
        for (int nt = 0; nt < 4; ++nt)
            b[nt] = *(const v8s*)(const void*)&w2b[(size_t)ks * 8192 + nt * 512];
        #pragma unroll
        for (int nt = 0; nt < 4; ++nt) {
            acc2[0][nt] = __builtin_amdgcn_mfma_f32_32x32x16_bf16(a0, b[nt], acc2[0][nt], 0, 0, 0);
            acc2[1][nt] = __builtin_amdgcn_mfma_f32_32x32x16_bf16(a1, b[nt], acc2[1][nt], 0, 0, 0);
        }
    }

    float* ot = out + t0 * 512;
    #pragma unroll
    for (int mt = 0; mt < 2; ++mt)
        #pragma unroll
        for (int nt = 0; nt < 4; ++nt)
            #pragma unroll
            for (int j = 0; j < 16; ++j) {
                int row = 32 * mt + (j & 3) + 8 * (j >> 2) + 4 * hi;
                int col = 128 * wv + 32 * nt + ln;
                ot[row * 512 + col] = acc2[mt][nt][j];
            }
}

extern "C" void kernel_launch(void* const* d_in, const int* in_sizes, int n_in,
                              void* d_out, int out_size, void* d_ws, size_t ws_size,
                              hipStream_t stream) {
    const float* x  = (const float*)d_in[0];
    const float* rw = (const float*)d_in[1];
    const float* rb = (const float*)d_in[2];
    const float* w1 = (const float*)d_in[3];
    const float* b1 = (const float*)d_in[4];
    const float* w2 = (const float*)d_in[5];
    const float* b2 = (const float*)d_in[6];

    unsigned short* w1p = (unsigned short*)d_ws;      // 131072 elems
    unsigned short* w2p = w1p + 131072;               // 147456 elems
    unsigned short* rp  = w2p + 147456;               // 16384 elems (total ~590 KB)

    moe_prep<<<1152, 256, 0, stream>>>(w1, w2, b2, rw, w1p, w2p, rp);
    moe_main<<<512, 256, 0, stream>>>(x, rb, b1, w1p, w2p, rp, (float*)d_out);
}

// Round 10
// 145.376 us; speedup vs baseline: 1.4726x; 1.0217x over previous
//
#include <hip/hip_runtime.h>
#include <hip/hip_bf16.h>
#include <math.h>

// TinyMoE: out = sum_e softmax(x@Wr)[e] * (gelu(x@w1[e]+b1[e]) @ w2[e] + b2[e])
// v11: v10 shell (32x32x16 MFMA, 64 tok/WG, 4 waves, (256,2); bank-conflict-free,
//      arch VGPR 88 -> ~80 regs headroom) + the pipeline that headroom enables:
//      - GEMM1: 2-stage named-register prefetch of b-frags (ks+1 issued before
//        compute of ks; 24 VGPR)
//      - GEMM2: two 2-ntile passes (acc 64) with 2-stage b prefetch; pass-0
//        stores overlap pass-1 compute (spreads the write burst)
//      - staging fp32->bf16 via v_cvt_pk_bf16_f32 (RNE, 1 op / 2 elems, ~5x less
//        staging VALU than the bit-twiddle; baseline was never cvt_pk)
//      Router fold on waves 0-1, in-reg softmax, H aliases X LDS (all verified).

typedef short v8s  __attribute__((ext_vector_type(8)));
typedef float v16f __attribute__((ext_vector_type(16)));

#define XS 520   // X LDS row stride (bf16): 512 + 8 pad
#define HS 296   // H LDS row stride: 288 (256 + 4 b2 rows + 28 zero) + 8 pad

__device__ __forceinline__ unsigned short f2bf(float f) {
    unsigned int u = __builtin_bit_cast(unsigned int, f);
    u += 0x7fffu + ((u >> 16) & 1u);
    return (unsigned short)(u >> 16);
}
__device__ __forceinline__ unsigned int cvtpk(float lo, float hi) {
    unsigned int r;
    asm("v_cvt_pk_bf16_f32 %0, %1, %2" : "=v"(r) : "v"(lo), "v"(hi));
    return r;
}
// exact-gelu via A&S 7.1.26 erf (|err|<=1.5e-7; harness-verified v7-v10)
__device__ __forceinline__ float gelu_fast(float v) {
    float s  = v * 0.70710678118f;
    float xa = fabsf(s);
    float t  = 1.0f / (1.0f + 0.3275911f * xa);
    float poly = t * (0.254829592f + t * (-0.284496736f + t * (1.421413741f +
                 t * (-1.453152027f + t * 1.061405429f))));
    float er = copysignf(1.0f - poly * __expf(-xa * xa), s);
    return 0.5f * v * (1.0f + er);
}

// ---- prep: pack weights into 32x32x16 B-fragment layout (v10-verified) ----
// Block = 32(N) x 16(K) bf16, [n_local*16 + k_local], 512 elems = 1KB.
// Lane l reads 16B at ((l&31)*16 + (l>>5)*8)*2 -> B[k][n], n=l&31, k=(l>>5)*8+j.
__global__ void moe_prep(const float* __restrict__ w1,   // (4,512,64)
                         const float* __restrict__ w2,   // (4,64,512)
                         const float* __restrict__ b2,   // (4,512)
                         const float* __restrict__ rw,   // (512,4)
                         unsigned short* __restrict__ w1p,
                         unsigned short* __restrict__ w2p,
                         unsigned short* __restrict__ rp) {
    int idx = blockIdx.x * 256 + threadIdx.x;
    if (idx < 131072) {
        int block = idx >> 9, within = idx & 511;
        int kstep = block >> 3, cb = block & 7;
        int n = within >> 4, kl = within & 15;
        int k = kstep * 16 + kl;
        int col = cb * 32 + n;
        int e = col >> 6, h = col & 63;
        w1p[idx] = f2bf(w1[(e * 512 + k) * 64 + h]);
    } else if (idx < 131072 + 147456) {
        int op = idx - 131072;
        int block = op >> 9, within = op & 511;
        int kstep = block >> 4, cb = block & 15;
        int n = within >> 4, kl = within & 15;
        int k = kstep * 16 + kl;
        int d = cb * 32 + n;
        float v = 0.f;
        if (k < 256) {
            int e = k >> 6, h = k & 63;
            v = w2[(e * 64 + h) * 512 + d];
        } else if (k < 260) {
            v = b2[(k - 256) * 512 + d];
        }
        w2p[op] = f2bf(v);
    } else if (idx < 131072 + 147456 + 16384) {
        int op = idx - (131072 + 147456);
        int kstep = op >> 9, within = op & 511;
        int n = within >> 4, kl = within & 15;
        int k = kstep * 16 + kl;
        float v = (n < 4) ? rw[k * 4 + n] : 0.f;
        rp[op] = f2bf(v);
    }
}

// ---- main fused kernel ----
__global__ __launch_bounds__(256, 2)
void moe_main(const float* __restrict__ x,
              const float* __restrict__ rb,
              const float* __restrict__ b1,
              const unsigned short* __restrict__ w1p,
              const unsigned short* __restrict__ w2p,
              const unsigned short* __restrict__ rp,
              float* __restrict__ out) {
    __shared__ __align__(16) unsigned short lx[64 * XS];   // X tile; H aliases after GEMM1
    __shared__ float lw[64 * 4];

    const int tid  = threadIdx.x;
    const int lane = tid & 63, wv = tid >> 6;
    const int ln = lane & 31, hi = lane >> 5;   // 32x32 frags: row/col=ln, k=hi*8+j
    const long t0 = (long)blockIdx.x * 64;

    // ---- phase 0: stage X tile (fp32 global -> bf16 LDS via cvt_pk) ----
    const float4* xt = (const float4*)(x + t0 * 512);
    #pragma unroll
    for (int it = 0; it < 32; ++it) {
        int F = it * 256 + tid;
        int row = F >> 7, c4 = F & 127;
        float4 v = xt[F];
        *(uint2*)&lx[row * XS + c4 * 4] = make_uint2(cvtpk(v.x, v.y), cvtpk(v.z, v.w));
    }
    __syncthreads();

    // ---- GEMM1: C1[64][256] = X @ W1'. Wave w = expert w (cols 64w..64w+64).
    //      Waves 0-1 also accumulate router logits. 2-stage b prefetch. ----
    v16f acc1[2][2];
    v16f accR;
    #pragma unroll
    for (int j = 0; j < 16; ++j) accR[j] = 0.f;
    #pragma unroll
    for (int mt = 0; mt < 2; ++mt)
        #pragma unroll
        for (int nt = 0; nt < 2; ++nt)
            #pragma unroll
            for (int j = 0; j < 16; ++j) acc1[mt][nt][j] = 0.f;

    const unsigned short* w1b = w1p + (size_t)(wv * 2) * 512 + ln * 16 + hi * 8;
    const unsigned short* rpb = rp + ln * 16 + hi * 8;

    #define LD1(B0, B1, BR, ks) do {                                               \
        B0 = *(const v8s*)(const void*)&w1b[(size_t)(ks) * 4096];                  \
        B1 = *(const v8s*)(const void*)&w1b[(size_t)(ks) * 4096 + 512];            \
        BR = *(const v8s*)(const void*)&rpb[(ks) * 512];                           \
    } while (0)

    #define MM1(B0, B1, BR, ks) do {                                               \
        v8s a0_ = *(const v8s*)(const void*)&lx[ln * XS + (ks) * 16 + hi * 8];     \
        v8s a1_ = *(const v8s*)(const void*)&lx[(32 + ln) * XS + (ks) * 16 + hi * 8]; \
        if (wv < 2) {                                                              \
            v8s ar_ = (wv == 0) ? a0_ : a1_;                                       \
            accR = __builtin_amdgcn_mfma_f32_32x32x16_bf16(ar_, BR, accR, 0, 0, 0);\
        }                                                                          \
        acc1[0][0] = __builtin_amdgcn_mfma_f32_32x32x16_bf16(a0_, B0, acc1[0][0], 0, 0, 0); \
        acc1[0][1] = __builtin_amdgcn_mfma_f32_32x32x16_bf16(a0_, B1, acc1[0][1], 0, 0, 0); \
        acc1[1][0] = __builtin_amdgcn_mfma_f32_32x32x16_bf16(a1_, B0, acc1[1][0], 0, 0, 0); \
        acc1[1][1] = __builtin_amdgcn_mfma_f32_32x32x16_bf16(a1_, B1, acc1[1][1], 0, 0, 0); \
    } while (0)

    {
        v8s pb0, pb1, pbr, qb0, qb1, qbr;
        LD1(pb0, pb1, pbr, 0);
        for (int kp = 0; kp < 16; ++kp) {
            LD1(qb0, qb1, qbr, 2 * kp + 1);      // prefetch odd ks
            MM1(pb0, pb1, pbr, 2 * kp);          // compute even ks
            if (kp < 15) LD1(pb0, pb1, pbr, 2 * kp + 2);   // prefetch next even
            MM1(qb0, qb1, qbr, 2 * kp + 1);      // compute odd ks
        }
    }

    // ---- in-reg softmax (waves 0-1): accR[j] = logit(row = 32wv + (j&3)+8*(j>>2)+4*hi,
    //      expert = ln), valid lanes ln<4 within 4-lane shfl groups ----
    if (wv < 2) {
        float rbv = rb[ln & 3];
        #pragma unroll
        for (int j = 0; j < 16; ++j) {
            float v = accR[j] + rbv;
            float m = fmaxf(v, __shfl_xor(v, 1));
            m = fmaxf(m, __shfl_xor(m, 2));
            float e = __expf(v - m);
            float s = e + __shfl_xor(e, 1);
            s += __shfl_xor(s, 2);
            if (ln < 4) {
                int row = 32 * wv + (j & 3) + 8 * (j >> 2) + 4 * hi;
                lw[row * 4 + ln] = e / s;
            }
        }
    }
    __syncthreads();   // lw visible; all waves done reading X; lx may now hold H

    // ---- epilogue: gelu(v+b1)*wt -> bf16 H[64][288] (aliasing lx) ----
    {
        float b1v[2];
        #pragma unroll
        for (int nt = 0; nt < 2; ++nt) b1v[nt] = b1[wv * 64 + 32 * nt + ln];
        #pragma unroll
        for (int mt = 0; mt < 2; ++mt) {
            #pragma unroll
            for (int j = 0; j < 16; ++j) {
                int row = 32 * mt + (j & 3) + 8 * (j >> 2) + 4 * hi;
                float wt = lw[row * 4 + wv];
                #pragma unroll
                for (int nt = 0; nt < 2; ++nt) {
                    float v = acc1[mt][nt][j] + b1v[nt];
                    float g = gelu_fast(v) * wt;
                    lx[row * HS + wv * 64 + 32 * nt + ln] = f2bf(g);
                }
            }
        }
        // router-weight cols (256..259) and zero pad (260..287)
        int r = tid >> 2, e = tid & 3;
        lx[r * HS + 256 + e] = f2bf(lw[tid]);
        #pragma unroll
        for (int i = 0; i < 7; ++i)
            lx[r * HS + 260 + e + 4 * i] = 0;
    }
    __syncthreads();

    // ---- GEMM2: OUT[64][512] = H[64][288] @ W2'. Wave w cols [128w,128w+128),
    //      two 2-ntile passes (acc 64); pass-0 stores overlap pass-1 compute. ----
    const unsigned short* w2b = w2p + (size_t)(wv * 4) * 512 + ln * 16 + hi * 8;
    float* ot = out + t0 * 512;

    #define LD2(D0, D1, ks, poff) do {                                             \
        D0 = *(const v8s*)(const void*)&w2b[(size_t)(ks) * 8192 + (poff)];         \
        D1 = *(const v8s*)(const void*)&w2b[(size_t)(ks) * 8192 + (poff) + 512];   \
    } while (0)

    #define MM2(D0, D1, ks) do {                                                   \
        v8s a0_ = *(const v8s*)(const void*)&lx[ln * HS + (ks) * 16 + hi * 8];     \
        v8s a1_ = *(const v8s*)(const void*)&lx[(32 + ln) * HS + (ks) * 16 + hi * 8]; \
        acc2[0][0] = __builtin_amdgcn_mfma_f32_32x32x16_bf16(a0_, D0, acc2[0][0], 0, 0, 0); \
        acc2[0][1] = __builtin_amdgcn_mfma_f32_32x32x16_bf16(a0_, D1, acc2[0][1], 0, 0, 0); \
        acc2[1][0] = __builtin_amdgcn_mfma_f32_32x32x16_bf16(a1_, D0, acc2[1][0], 0, 0, 0); \
        acc2[1][1] = __builtin_amdgcn_mfma_f32_32x32x16_bf16(a1_, D1, acc2[1][1], 0, 0, 0); \
    } while (0)

    #pragma unroll 1
    for (int pass = 0; pass < 2; ++pass) {
        const int poff = pass * 1024;          // 2 colblocks * 512
        v16f acc2[2][2];
        #pragma unroll
        for (int mt = 0; mt < 2; ++mt)
            #pragma unroll
            for (int nt = 0; nt < 2; ++nt)
                #pragma unroll
                for (int j = 0; j < 16; ++j) acc2[mt][nt][j] = 0.f;

        v8s pd0, pd1, qd0, qd1;
        LD2(pd0, pd1, 0, poff);
        for (int kp = 0; kp < 9; ++kp) {       // 18 ks = 9 pairs exactly
            LD2(qd0, qd1, 2 * kp + 1, poff);
            MM2(pd0, pd1, 2 * kp);
            if (kp < 8) LD2(pd0, pd1, 2 * kp + 2, poff);
            MM2(qd0, qd1, 2 * kp + 1);
        }

        #pragma unroll
        for (int mt = 0; mt < 2; ++mt)
            #pragma unroll
            for (int nt = 0; nt < 2; ++nt)
                #pragma unroll
                for (int j = 0; j < 16; ++j) {
                    int row = 32 * mt + (j & 3) + 8 * (j >> 2) + 4 * hi;
                    int col = 128 * wv + 32 * (pass * 2 + nt) + ln;
                    ot[row * 512 + col] = acc2[mt][nt][j];
                }
    }
    #undef LD1
    #undef MM1
    #undef LD2
    #undef MM2
}

extern "C" void kernel_launch(void* const* d_in, const int* in_sizes, int n_in,
                              void* d_out, int out_size, void* d_ws, size_t ws_size,
                              hipStream_t stream) {
    const float* x  = (const float*)d_in[0];
    const float* rw = (const float*)d_in[1];
    const float* rb = (const float*)d_in[2];
    const float* w1 = (const float*)d_in[3];
    const float* b1 = (const float*)d_in[4];
    const float* w2 = (const float*)d_in[5];
    const float* b2 = (const float*)d_in[6];

    unsigned short* w1p = (unsigned short*)d_ws;      // 131072 elems
    unsigned short* w2p = w1p + 131072;               // 147456 elems
    unsigned short* rp  = w2p + 147456;               // 16384 elems (total ~590 KB)

    moe_prep<<<1152, 256, 0, stream>>>(w1, w2, b2, rw, w1p, w2p, rp);
    moe_main<<<512, 256, 0, stream>>>(x, rb, b1, w1p, w2p, rp, (float*)d_out);
}

// Round 11
// 142.958 us; speedup vs baseline: 1.4975x; 1.0169x over previous
//
#include <hip/hip_runtime.h>
#include <hip/hip_bf16.h>
#include <math.h>

// TinyMoE: out = sum_e softmax(x@Wr)[e] * (gelu(x@w1[e]+b1[e]) @ w2[e] + b2[e])
// v12 = v1 (best measured, 51us moe_main) with ONE change: GEMM2 runs 32x32x16
//       (v10-verified packing/indexing/C-layout). v10 isolated: 32x32 is worse for
//       GEMM1 (too few MFMA cycles per iteration to hide weight loads) but better
//       for GEMM2 (same load count, 17% less MFMA pipe time, zero bank conflicts).
//       Everything else (staging, router phase, softmax, epilogue, GEMM1) is
//       byte-identical to v1.

typedef short v8s  __attribute__((ext_vector_type(8)));
typedef float v4f  __attribute__((ext_vector_type(4)));
typedef float v16f __attribute__((ext_vector_type(16)));

#define XS 520   // X LDS row stride (bf16 elems): 512 + 8 pad
#define HS 296   // H LDS row stride: 288 (=256 + 4 b2-weight rows + 28 zero pad) + 8 pad

__device__ __forceinline__ unsigned short f2bf(float f) {
    unsigned int u = __builtin_bit_cast(unsigned int, f);
    u += 0x7fffu + ((u >> 16) & 1u);
    return (unsigned short)(u >> 16);
}

// ---- prep: pack weights into bf16 MFMA B-fragment layouts ----
// w1p/rp: 16(N) x 32(K) blocks (16x16x32 path, v1-verified):
//   [n_local*32 + k_local], lane l reads 16B at ((l&15)*32 + (l>>4)*8)*2.
// w2p: 32(N) x 16(K) blocks (32x32x16 path, v10-verified):
//   [n_local*16 + k_local], lane l reads 16B at ((l&31)*16 + (l>>5)*8)*2.
__global__ void moe_prep(const float* __restrict__ w1,   // (4,512,64)
                         const float* __restrict__ w2,   // (4,64,512)
                         const float* __restrict__ b2,   // (4,512)
                         const float* __restrict__ rw,   // (512,4)
                         unsigned short* __restrict__ w1p,
                         unsigned short* __restrict__ w2p,
                         unsigned short* __restrict__ rp) {
    int idx = blockIdx.x * 256 + threadIdx.x;
    if (idx < 131072) {
        // W1' [K=512][N=256], 16x32 blocks: block = kb*16 + cb
        int block = idx >> 9, within = idx & 511;
        int kb = block >> 4, cb = block & 15;
        int n = within >> 5, kl = within & 31;
        int k = kb * 32 + kl;
        int col = cb * 16 + n;          // e = col>>6, h = col&63
        int e = col >> 6, h = col & 63;
        w1p[idx] = f2bf(w1[(e * 512 + k) * 64 + h]);
    } else if (idx < 131072 + 147456) {
        // W2' [Kpad=288 -> 18 ksteps][16 col-blocks of 32]; k 256..259 = b2, >=260 zero
        int op = idx - 131072;
        int block = op >> 9, within = op & 511;
        int kstep = block >> 4, cb = block & 15;
        int n = within >> 4, kl = within & 15;
        int k = kstep * 16 + kl;
        int d = cb * 32 + n;
        float v = 0.f;
        if (k < 256) {
            int e = k >> 6, h = k & 63;
            v = w2[(e * 64 + h) * 512 + d];
        } else if (k < 260) {
            v = b2[(k - 256) * 512 + d];
        }
        w2p[op] = f2bf(v);
    } else if (idx < 131072 + 147456 + 8192) {
        // router W [K=512][N=16] (cols >=4 zero), 16x32 blocks, block = kb
        int op = idx - (131072 + 147456);
        int kb = op >> 9, within = op & 511;
        int n = within >> 5, kl = within & 31;
        int k = kb * 32 + kl;
        float v = (n < 4) ? rw[k * 4 + n] : 0.f;
        rp[op] = f2bf(v);
    }
}

// ---- main fused kernel ----
__global__ __launch_bounds__(256, 2)
void moe_main(const float* __restrict__ x,
              const float* __restrict__ rb,
              const float* __restrict__ b1,
              const unsigned short* __restrict__ w1p,
              const unsigned short* __restrict__ w2p,
              const unsigned short* __restrict__ rp,
              float* __restrict__ out) {
    // X tile [64][XS] bf16 = 66560 B; H tile [64][HS] aliases it after GEMM1.
    __shared__ __align__(16) unsigned short lx[64 * XS];
    __shared__ float llog[64 * 4];
    __shared__ float lw[64 * 4];

    const int tid  = threadIdx.x;
    const int lane = tid & 63, wv = tid >> 6;
    const int lr = lane & 15, lq = lane >> 4;   // 16x16: A m=lr, k=lq*8+j ; B n=lr ; C col=lr, row=lq*4+r
    const int ln = lane & 31, hi = lane >> 5;   // 32x32: A row=ln ; B col=ln ; k=hi*8+j
    const long t0 = (long)blockIdx.x * 64;

    // ---- phase 0: stage X tile (fp32 global -> bf16 LDS) ----
    const float4* xt = (const float4*)(x + t0 * 512);
    #pragma unroll
    for (int it = 0; it < 32; ++it) {
        int F = it * 256 + tid;            // float4 index in 64x512 tile
        int row = F >> 7, c4 = F & 127;
        float4 v = xt[F];
        unsigned int p0 = (unsigned int)f2bf(v.x) | ((unsigned int)f2bf(v.y) << 16);
        unsigned int p1 = (unsigned int)f2bf(v.z) | ((unsigned int)f2bf(v.w) << 16);
        *(uint2*)&lx[row * XS + c4 * 4] = make_uint2(p0, p1);
    }
    __syncthreads();

    // ---- phase 1: router logits via MFMA (wave w -> tokens 16w..16w+15), softmax ----
    {
        v4f accR; accR[0] = accR[1] = accR[2] = accR[3] = 0.f;
        #pragma unroll
        for (int kb = 0; kb < 16; ++kb) {
            v8s a = *(const v8s*)(const void*)&lx[(16 * wv + lr) * XS + kb * 32 + lq * 8];
            v8s b = *(const v8s*)(const void*)&rp[kb * 512 + lr * 32 + lq * 8];
            accR = __builtin_amdgcn_mfma_f32_16x16x32_bf16(a, b, accR, 0, 0, 0);
        }
        if (lr < 4) {
            #pragma unroll
            for (int r = 0; r < 4; ++r)
                llog[(16 * wv + lq * 4 + r) * 4 + lr] = accR[r];
        }
    }
    __syncthreads();
    if (tid < 64) {
        float l[4];
        #pragma unroll
        for (int e = 0; e < 4; ++e) l[e] = llog[tid * 4 + e] + rb[e];
        float mx = fmaxf(fmaxf(l[0], l[1]), fmaxf(l[2], l[3]));
        float ex[4], s = 0.f;
        #pragma unroll
        for (int e = 0; e < 4; ++e) { ex[e] = expf(l[e] - mx); s += ex[e]; }
        float inv = 1.f / s;
        #pragma unroll
        for (int e = 0; e < 4; ++e) lw[tid * 4 + e] = ex[e] * inv;
    }
    __syncthreads();

    // ---- phase 2: GEMM1  C1[64][256] = X @ W1'; wave w owns cols [64w,64w+64) = expert w ----
    v4f acc1[4][4];
    #pragma unroll
    for (int mt = 0; mt < 4; ++mt)
        #pragma unroll
        for (int nt = 0; nt < 4; ++nt)
            acc1[mt][nt][0] = acc1[mt][nt][1] = acc1[mt][nt][2] = acc1[mt][nt][3] = 0.f;

    for (int kb = 0; kb < 16; ++kb) {
        v8s a[4], b[4];
        #pragma unroll
        for (int mt = 0; mt < 4; ++mt)
            a[mt] = *(const v8s*)(const void*)&lx[(16 * mt + lr) * XS + kb * 32 + lq * 8];
        #pragma unroll
        for (int nt = 0; nt < 4; ++nt)
            b[nt] = *(const v8s*)(const void*)&w1p[(size_t)(kb * 16 + wv * 4 + nt) * 512 + lr * 32 + lq * 8];
        #pragma unroll
        for (int mt = 0; mt < 4; ++mt)
            #pragma unroll
            for (int nt = 0; nt < 4; ++nt)
                acc1[mt][nt] = __builtin_amdgcn_mfma_f32_16x16x32_bf16(a[mt], b[nt], acc1[mt][nt], 0, 0, 0);
    }
    __syncthreads();   // all waves done reading X; lx may now be overwritten by H

    // epilogue: gelu(v+b1)*router_weight -> bf16 H[64][288] (cols 256..259 = router weights)
    {
        float b1v[4];
        #pragma unroll
        for (int nt = 0; nt < 4; ++nt) b1v[nt] = b1[wv * 64 + nt * 16 + lr];
        #pragma unroll
        for (int mt = 0; mt < 4; ++mt) {
            #pragma unroll
            for (int r = 0; r < 4; ++r) {
                int row = 16 * mt + lq * 4 + r;
                float wt = lw[row * 4 + wv];
                #pragma unroll
                for (int nt = 0; nt < 4; ++nt) {
                    float v = acc1[mt][nt][r] + b1v[nt];
                    float g = 0.5f * v * (1.f + erff(v * 0.70710678118f)) * wt;
                    lx[row * HS + wv * 64 + nt * 16 + lr] = f2bf(g);
                }
            }
        }
        // append router-weight cols (k=256..259) and zero pad (260..287)
        int r = tid >> 2, e = tid & 3;
        lx[r * HS + 256 + e] = f2bf(lw[tid]);
        #pragma unroll
        for (int i = 0; i < 7; ++i)
            lx[r * HS + 260 + e + 4 * i] = 0;
    }
    __syncthreads();

    // ---- phase 3: GEMM2 (32x32x16)  OUT[64][512] = H[64][288] @ W2';
    //      wave w owns cols [128w,128w+128) = 4 col-blocks of 32 ----
    v16f acc2[2][4];
    #pragma unroll
    for (int mt = 0; mt < 2; ++mt)
        #pragma unroll
        for (int nt = 0; nt < 4; ++nt)
            #pragma unroll
            for (int j = 0; j < 16; ++j) acc2[mt][nt][j] = 0.f;

    const unsigned short* w2b = w2p + (size_t)(wv * 4) * 512 + ln * 16 + hi * 8;

    for (int ks = 0; ks < 18; ++ks) {
        v8s a0 = *(const v8s*)(const void*)&lx[ln * HS + ks * 16 + hi * 8];
        v8s a1 = *(const v8s*)(const void*)&lx[(32 + ln) * HS + ks * 16 + hi * 8];
        v8s b[4];
        #pragma unroll
        for (int nt = 0; nt < 4; ++nt)
            b[nt] = *(const v8s*)(const void*)&w2b[(size_t)ks * 8192 + nt * 512];
        #pragma unroll
        for (int nt = 0; nt < 4; ++nt) {
            acc2[0][nt] = __builtin_amdgcn_mfma_f32_32x32x16_bf16(a0, b[nt], acc2[0][nt], 0, 0, 0);
            acc2[1][nt] = __builtin_amdgcn_mfma_f32_32x32x16_bf16(a1, b[nt], acc2[1][nt], 0, 0, 0);
        }
    }

    float* ot = out + t0 * 512;
    #pragma unroll
    for (int mt = 0; mt < 2; ++mt)
        #pragma unroll
        for (int nt = 0; nt < 4; ++nt)
            #pragma unroll
            for (int j = 0; j < 16; ++j) {
                int row = 32 * mt + (j & 3) + 8 * (j >> 2) + 4 * hi;
                int col = 128 * wv + 32 * nt + ln;
                ot[row * 512 + col] = acc2[mt][nt][j];
            }
}

extern "C" void kernel_launch(void* const* d_in, const int* in_sizes, int n_in,
                              void* d_out, int out_size, void* d_ws, size_t ws_size,
                              hipStream_t stream) {
    const float* x  = (const float*)d_in[0];
    const float* rw = (const float*)d_in[1];
    const float* rb = (const float*)d_in[2];
    const float* w1 = (const float*)d_in[3];
    const float* b1 = (const float*)d_in[4];
    const float* w2 = (const float*)d_in[5];
    const float* b2 = (const float*)d_in[6];

    unsigned short* w1p = (unsigned short*)d_ws;      // 131072 elems
    unsigned short* w2p = w1p + 131072;               // 147456 elems
    unsigned short* rp  = w2p + 147456;               // 8192 elems  (total ~573 KB)

    moe_prep<<<1120, 256, 0, stream>>>(w1, w2, b2, rw, w1p, w2p, rp);
    moe_main<<<512, 256, 0, stream>>>(x, rb, b1, w1p, w2p, rp, (float*)d_out);
}